// Round 1
// baseline (6070.782 us; speedup 1.0000x reference)
//
#include <hip/hip_runtime.h>

#define NB 2
#define ND 128
#define NN 8192
#define TK 128
#define KNNK 32
#define ROWS 4
#define NT 256

typedef unsigned long long u64;
typedef long long i64;

// ws layout:
// [0, 8MB)        ws_h   : float [2][8192][128]   (pre-GN h)
// [8MB, 16MB)     ws_kin : float [2][8192][32][4] (corr,dx,dy,dz per knn slot)
// [16MB, +576B)   stats  : u64   ocsum[16], ocsq[16], km1[8], km2[32]  (fixed-point)
// [16MB+1KB,+256) fstats : f32   ocmean[16], ocrstd[16], kcmean[16], kcrstd[16]

__device__ __forceinline__ unsigned int f2key(float v){
    unsigned int u = __float_as_uint(v);
    return u ^ ((unsigned int)((int)u >> 31) | 0x80000000u);
}

// ---------------- K0: zero the stat accumulators ----------------
__global__ void k0_zero(u64* __restrict__ stats){
    const int t = threadIdx.x;
    if (t < 72) stats[t] = 0ull;
}

// ---------------- K1: corr GEMM + top-128 + vox hist + h + knn ----------------
__global__ __launch_bounds__(NT, 1) void k1_corr_topk(
    const float* __restrict__ fmap1, const float* __restrict__ fmap2,
    const float* __restrict__ xyz2, const float* __restrict__ coords,
    const float* __restrict__ w1, const float* __restrict__ b1,
    float* __restrict__ ws_h, float* __restrict__ ws_kin,
    u64* __restrict__ stats)
{
    __shared__ float qs[ROWS*ND];
    __shared__ unsigned int hist[256];
    __shared__ int suff[256];
    __shared__ int scol[TK];
    __shared__ float sval[TK], sx[TK], sy[TK], sz[TK], sdist[TK];
    __shared__ u64 vadd[81];
    __shared__ unsigned int vcnt[81];
    __shared__ float voxn[81];
    __shared__ int eqcol[256];
    __shared__ u64 wg_ocsum[8], wg_ocsq[8], wg_km1[4], wg_km2[16];
    __shared__ int cnt_sel, cnt_eq, binB_s, kneed_s;

    const int t = threadIdx.x;
    // XCD-aware: batch 0 -> XCDs 0-3, batch 1 -> XCDs 4-7 (fmap2 4MB fits one L2)
    const int xcd = blockIdx.x & 7;
    const int b = xcd >> 2;
    const int i0 = (((xcd & 3) << 9) + (int)(blockIdx.x >> 3)) * ROWS;

    for (int u = t; u < ROWS*ND; u += NT){
        const int r = u & (ROWS-1), d = u >> 2;
        qs[r*ND + d] = fmap1[((size_t)b*ND + d)*NN + (i0 + r)];
    }
    if (t < 8){ wg_ocsum[t]=0ull; wg_ocsq[t]=0ull; }
    if (t < 4) wg_km1[t]=0ull;
    if (t < 16) wg_km2[t]=0ull;
    __syncthreads();

    // ---- GEMM: 4 rows x 8192 cols, 32 cols/thread, acc in registers ----
    float a0[32], a1[32], a2[32], a3[32];
    #pragma unroll
    for (int j=0;j<32;j++){ a0[j]=0.f; a1[j]=0.f; a2[j]=0.f; a3[j]=0.f; }

    const float* f2b = fmap2 + (size_t)b*ND*NN;
    for (int dt=0; dt<ND/4; ++dt){
        const float4 q0 = *(const float4*)&qs[0*ND + dt*4];
        const float4 q1 = *(const float4*)&qs[1*ND + dt*4];
        const float4 q2 = *(const float4*)&qs[2*ND + dt*4];
        const float4 q3 = *(const float4*)&qs[3*ND + dt*4];
        const float* p0 = f2b + (size_t)(dt*4)*NN + t;
        #pragma unroll
        for (int j=0;j<32;j++){
            const float v0 = p0[j*NT];
            const float v1 = p0[j*NT + NN];
            const float v2 = p0[j*NT + 2*NN];
            const float v3 = p0[j*NT + 3*NN];
            a0[j] += q0.x*v0 + q0.y*v1 + q0.z*v2 + q0.w*v3;
            a1[j] += q1.x*v0 + q1.y*v1 + q1.z*v2 + q1.w*v3;
            a2[j] += q2.x*v0 + q2.y*v1 + q2.z*v2 + q2.w*v3;
            a3[j] += q3.x*v0 + q3.y*v1 + q3.z*v2 + q3.w*v3;
        }
    }
    const float scl = 1.0f / sqrtf(128.0f);
    #pragma unroll
    for (int j=0;j<32;j++){ a0[j]*=scl; a1[j]*=scl; a2[j]*=scl; a3[j]*=scl; }

    // ---- per-row: radix-select top-128 (set semantics), vox, h, knn ----
    auto phaseB = [&](const float (&av)[32], const int i){
        int k = TK;
        unsigned int prefix = 0u;
        #pragma unroll
        for (int pass=0; pass<4; ++pass){
            const int shift = 24 - pass*8;
            hist[t] = 0u;
            __syncthreads();
            #pragma unroll
            for (int j=0;j<32;j++){
                const unsigned int key = f2key(av[j]);
                if (pass==0 || (key >> (shift+8)) == prefix)
                    atomicAdd(&hist[(key>>shift)&255], 1u);
            }
            __syncthreads();
            suff[t] = (int)hist[t];
            __syncthreads();
            #pragma unroll
            for (int off=1; off<256; off<<=1){
                const int addv = (t+off<256) ? suff[t+off] : 0;
                __syncthreads();
                suff[t] += addv;
                __syncthreads();
            }
            const int s_here = suff[t];
            const int s_next = (t<255) ? suff[t+1] : 0;
            if (s_here >= k && s_next < k){ binB_s = t; kneed_s = k - s_next; }
            __syncthreads();
            prefix = (prefix << 8) | (unsigned int)binB_s;
            k = kneed_s;
            __syncthreads();
        }
        const unsigned int T = prefix;
        if (t==0){ cnt_sel=0; cnt_eq=0; }
        __syncthreads();
        #pragma unroll
        for (int j=0;j<32;j++){
            const unsigned int key = f2key(av[j]);
            if (key > T){
                const int p = atomicAdd(&cnt_sel, 1);
                scol[p] = t + NT*j; sval[p] = av[j];
            } else if (key == T){
                const int p = atomicAdd(&cnt_eq, 1);
                if (p < 256) eqcol[p] = t + NT*j;
            }
        }
        __syncthreads();
        {
            const int nG = cnt_sel;
            const int k4 = TK - nG;
            int m = cnt_eq; if (m > 256) m = 256;
            const float eqval = __uint_as_float((T & 0x80000000u) ? (T ^ 0x80000000u) : ~T);
            if (t < m){
                const int myc = eqcol[t];
                int rank = 0;
                for (int u2=0; u2<m; ++u2) rank += (eqcol[u2] < myc) ? 1 : 0;
                if (rank < k4){ const int p = atomicAdd(&cnt_sel, 1); scol[p]=myc; sval[p]=eqval; }
            }
        }
        __syncthreads();

        const float cx = coords[((size_t)b*NN + i)*3 + 0];
        const float cy = coords[((size_t)b*NN + i)*3 + 1];
        const float cz = coords[((size_t)b*NN + i)*3 + 2];
        if (t < 81){ vadd[t]=0ull; vcnt[t]=0u; }
        if (t < TK){
            const float* pp = &xyz2[((size_t)b*NN + scol[t])*3];
            sx[t]=pp[0]; sy[t]=pp[1]; sz[t]=pp[2];
        }
        __syncthreads();
        if (t < TK){
            const float val = sval[t];
            const float dx = sx[t]-cx, dy = sy[t]-cy, dz = sz[t]-cz;
            sdist[t] = dx*dx + dy*dy + dz*dz;
            #pragma unroll
            for (int lvl=0; lvl<3; ++lvl){
                const float rs = 0.25f * (float)(1<<lvl);
                const float fx = rintf(dx/rs), fy = rintf(dy/rs), fz = rintf(dz/rs);
                if (fabsf(fx)<=1.f && fabsf(fy)<=1.f && fabsf(fz)<=1.f){
                    const int bin = lvl*27 + ((int)fx+1)*9 + ((int)fy+1)*3 + ((int)fz+1);
                    atomicAdd(&vadd[bin], (u64)llrintf(val*67108864.f));   // 2^26 fixed point
                    atomicAdd(&vcnt[bin], 1u);
                }
            }
        }
        __syncthreads();
        if (t < 81){
            const float addv = (float)(i64)vadd[t] * (1.f/67108864.f);
            float c = (float)vcnt[t]; if (c < 1.f) c = 1.f;
            voxn[t] = addv / c;
        }
        __syncthreads();
        if (t < ND){
            float h = b1[t];
            #pragma unroll
            for (int j=0;j<81;j++) h += w1[t*81+j]*voxn[j];
            ws_h[((size_t)b*NN + i)*ND + t] = h;
            const int g = t >> 4;
            atomicAdd(&wg_ocsum[g], (u64)llrintf(h*1048576.f));       // 2^20 fixed point
            atomicAdd(&wg_ocsq[g],  (u64)llrintf(h*h*1048576.f));
        }
        if (t < TK){
            const float my = sdist[t];
            int rank = 0;
            for (int u2=0; u2<TK; ++u2){
                const float o = sdist[u2];
                rank += (o < my || (o == my && u2 < t)) ? 1 : 0;
            }
            if (rank < KNNK){
                const float dx = sx[t]-cx, dy = sy[t]-cy, dz = sz[t]-cz;
                float* kp = &ws_kin[(((size_t)b*NN + i)*KNNK + rank)*4];
                kp[0]=sval[t]; kp[1]=dx; kp[2]=dy; kp[3]=dz;
                const float kv[4] = {sval[t], dx, dy, dz};
                #pragma unroll
                for (int a2=0;a2<4;a2++){
                    atomicAdd(&wg_km1[a2], (u64)llrintf(kv[a2]*1048576.f));
                    #pragma unroll
                    for (int b2=0;b2<4;b2++)
                        atomicAdd(&wg_km2[a2*4+b2], (u64)llrintf(kv[a2]*kv[b2]*1048576.f));
                }
            }
        }
        __syncthreads();
    };

    phaseB(a0, i0+0);
    phaseB(a1, i0+1);
    phaseB(a2, i0+2);
    phaseB(a3, i0+3);

    if (t < 8){ atomicAdd(&stats[b*8 + t], wg_ocsum[t]); atomicAdd(&stats[16 + b*8 + t], wg_ocsq[t]); }
    if (t < 4){ atomicAdd(&stats[32 + b*4 + t], wg_km1[t]); }
    if (t < 16){ atomicAdd(&stats[40 + b*16 + t], wg_km2[t]); }
}

// ---------------- K2: finalize GN statistics (f64, tiny) ----------------
__global__ void k2_stats(const u64* __restrict__ stats, float* __restrict__ fstats,
                         const float* __restrict__ kcw, const float* __restrict__ kcb)
{
    const int t = threadIdx.x;
    if (t < 16){  // oc GN: groups of 16 channels x 8192 points
        const double S = (double)(i64)stats[t];
        const double Q = (double)(i64)stats[16+t];
        const double cnt = 16.0*8192.0;
        const double mean = S / 1048576.0 / cnt;
        const double var  = Q / 1048576.0 / cnt - mean*mean;
        fstats[t]    = (float)mean;
        fstats[16+t] = (float)(1.0/sqrt(var + 1e-5));
    }
    if (t >= 32 && t < 48){  // kc GN: derived from kin 4x4 moments through the 1x1 conv
        const int u = t - 32;
        const int b = u >> 3, g = u & 7;
        double M1[4], M2[4][4];
        for (int a=0;a<4;a++) M1[a] = (double)(i64)stats[32 + b*4 + a] / 1048576.0;
        for (int a=0;a<4;a++) for (int c=0;c<4;c++)
            M2[a][c] = (double)(i64)stats[40 + b*16 + a*4 + c] / 1048576.0;
        const double cnt = 8192.0*32.0;
        double SUM=0.0, SSQ=0.0;
        for (int c = g*8; c < g*8+8; ++c){
            double wv[4]; for (int a=0;a<4;a++) wv[a] = (double)kcw[c*4+a];
            const double bc = (double)kcb[c];
            double sc = bc*cnt;
            double qc = bc*bc*cnt;
            for (int a=0;a<4;a++){
                sc += wv[a]*M1[a];
                qc += 2.0*bc*wv[a]*M1[a];
                for (int e=0;e<4;e++) qc += wv[a]*wv[e]*M2[a][e];
            }
            SUM += sc; SSQ += qc;
        }
        const double denom = 8.0*cnt;
        const double mean = SUM/denom;
        const double var  = SSQ/denom - mean*mean;
        fstats[32+u] = (float)mean;
        fstats[48+u] = (float)(1.0/sqrt(var + 1e-5));
    }
}

// ---------------- K3a: GN + PReLU + W2 (vox branch), writes out ----------------
__global__ __launch_bounds__(NT, 2) void k3a_vox(
    const float* __restrict__ ws_h, const float* __restrict__ fstats,
    const float* __restrict__ gnw, const float* __restrict__ gnb,
    const float* __restrict__ pr, const float* __restrict__ w2,
    const float* __restrict__ b2, float* __restrict__ out)
{
    const int tid = blockIdx.x*NT + threadIdx.x;
    const int b = tid >> 13, n = tid & (NN-1);
    const float a = pr[0];
    float p[ND];
    const float4* hp = (const float4*)&ws_h[(size_t)tid*ND];
    #pragma unroll
    for (int cc=0; cc<ND/4; ++cc){
        const float4 hv = hp[cc];
        const float hvv[4] = {hv.x, hv.y, hv.z, hv.w};
        #pragma unroll
        for (int q=0;q<4;q++){
            const int c = cc*4+q;
            const int g = c >> 4;
            const float hn = (hvv[q] - fstats[b*8+g]) * fstats[16+b*8+g] * gnw[c] + gnb[c];
            p[c] = hn >= 0.f ? hn : a*hn;
        }
    }
    for (int o=0;o<64;++o){
        float acc = b2[o];
        #pragma unroll
        for (int c=0;c<ND;c++) acc = fmaf(w2[o*ND+c], p[c], acc);
        out[(size_t)b*64*NN + (size_t)o*NN + n] = acc;
    }
}

// ---------------- K3b: knn conv + GN + PReLU + maxpool + ko, adds into out ----------------
__global__ __launch_bounds__(NT, 2) void k3b_knn(
    const float* __restrict__ ws_kin, const float* __restrict__ fstats,
    const float* __restrict__ kcw, const float* __restrict__ kcb,
    const float* __restrict__ gnw, const float* __restrict__ gnb,
    const float* __restrict__ pr, const float* __restrict__ kow,
    const float* __restrict__ kob, float* __restrict__ out)
{
    __shared__ float kml[64*NT];
    const int t = threadIdx.x;
    const int tid = blockIdx.x*NT + t;
    const int b = tid >> 13, n = tid & (NN-1);
    const float a = pr[0];
    float kin[TK];  // 32 slots x 4
    const float4* kp = (const float4*)&ws_kin[(size_t)tid*KNNK*4];
    #pragma unroll
    for (int kk=0; kk<KNNK; ++kk){
        const float4 v = kp[kk];
        kin[kk*4+0]=v.x; kin[kk*4+1]=v.y; kin[kk*4+2]=v.z; kin[kk*4+3]=v.w;
    }
    for (int c=0;c<64;++c){
        const int g = c >> 3;
        const float mean = fstats[32 + b*8 + g];
        const float rstd = fstats[48 + b*8 + g];
        const float gw = rstd * gnw[c];
        const float gb = gnb[c] - mean*gw;
        const float w0=kcw[c*4], w1v=kcw[c*4+1], w2v=kcw[c*4+2], w3=kcw[c*4+3], bc=kcb[c];
        float mx = -3.0e38f;
        #pragma unroll
        for (int kk=0; kk<KNNK; ++kk){
            float kf = bc + w0*kin[kk*4] + w1v*kin[kk*4+1] + w2v*kin[kk*4+2] + w3*kin[kk*4+3];
            float hn = kf*gw + gb;
            hn = hn >= 0.f ? hn : a*hn;
            mx = fmaxf(mx, hn);
        }
        kml[c*NT + t] = mx;
    }
    __syncthreads();
    for (int o=0;o<64;++o){
        float acc = kob[o];
        #pragma unroll
        for (int c=0;c<64;c++) acc = fmaf(kow[o*64+c], kml[c*NT+t], acc);
        const size_t oi = (size_t)b*64*NN + (size_t)o*NN + n;
        out[oi] += acc;
    }
}

extern "C" void kernel_launch(void* const* d_in, const int* in_sizes, int n_in,
                              void* d_out, int out_size, void* d_ws, size_t ws_size,
                              hipStream_t stream)
{
    const float* fmap1   = (const float*)d_in[0];
    const float* fmap2   = (const float*)d_in[1];
    const float* xyz2    = (const float*)d_in[2];
    const float* coords  = (const float*)d_in[3];
    const float* oc_w1   = (const float*)d_in[4];
    const float* oc_b1   = (const float*)d_in[5];
    const float* oc_gn_w = (const float*)d_in[6];
    const float* oc_gn_b = (const float*)d_in[7];
    const float* oc_pr   = (const float*)d_in[8];
    const float* oc_w2   = (const float*)d_in[9];
    const float* oc_b2   = (const float*)d_in[10];
    const float* kc_w    = (const float*)d_in[11];
    const float* kc_b    = (const float*)d_in[12];
    const float* kc_gn_w = (const float*)d_in[13];
    const float* kc_gn_b = (const float*)d_in[14];
    const float* kc_pr   = (const float*)d_in[15];
    const float* ko_w    = (const float*)d_in[16];
    const float* ko_b    = (const float*)d_in[17];

    char* ws = (char*)d_ws;
    float* ws_h   = (float*)ws;
    float* ws_kin = (float*)(ws + (size_t)8*1024*1024);
    u64*   stats  = (u64*)  (ws + (size_t)16*1024*1024);
    float* fstats = (float*)(ws + (size_t)16*1024*1024 + 1024);
    float* out    = (float*)d_out;

    k0_zero<<<dim3(1), dim3(128), 0, stream>>>(stats);
    k1_corr_topk<<<dim3(4096), dim3(NT), 0, stream>>>(
        fmap1, fmap2, xyz2, coords, oc_w1, oc_b1, ws_h, ws_kin, stats);
    k2_stats<<<dim3(1), dim3(64), 0, stream>>>(stats, fstats, kc_w, kc_b);
    k3a_vox<<<dim3(64), dim3(NT), 0, stream>>>(
        ws_h, fstats, oc_gn_w, oc_gn_b, oc_pr, oc_w2, oc_b2, out);
    k3b_knn<<<dim3(64), dim3(NT), 0, stream>>>(
        ws_kin, fstats, kc_w, kc_b, kc_gn_w, kc_gn_b, kc_pr, ko_w, ko_b, out);
}

// Round 2
// 1517.331 us; speedup vs baseline: 4.0010x; 4.0010x over previous
//
#include <hip/hip_runtime.h>

#define ND 128
#define NN 8192
#define TK 128
#define KNNK 32
#define ROWS 8
#define NT 1024
#define GSZ 4

typedef unsigned long long u64;
typedef long long i64;

// ws layout:
// [0, 8MB)        ws_h   : float [2][8192][128]   (pre-GN h)
// [8MB, 16MB)     ws_kin : float [2][8192][32][4] (corr,dx,dy,dz per knn slot)
// [16MB, +576B)   stats  : u64   ocsum[16], ocsq[16], km1[8], km2[32]  (fixed-point)
// [16MB+1KB,+256) fstats : f32   ocmean[16], ocrstd[16], kcmean[16], kcrstd[16]

__device__ __forceinline__ unsigned int f2key(float v){
    unsigned int u = __float_as_uint(v);
    return u ^ ((unsigned int)((int)u >> 31) | 0x80000000u);
}

// ---------------- K0: zero the stat accumulators ----------------
__global__ void k0_zero(u64* __restrict__ stats){
    const int t = threadIdx.x;
    if (t < 72) stats[t] = 0ull;
}

// ---------------- K1: corr GEMM + top-128 + vox hist + h + knn ----------------
__global__ __launch_bounds__(NT, 4) void k1_corr_topk(
    const float* __restrict__ fmap1, const float* __restrict__ fmap2,
    const float* __restrict__ xyz2, const float* __restrict__ coords,
    const float* __restrict__ w1, const float* __restrict__ b1,
    float* __restrict__ ws_h, float* __restrict__ ws_kin,
    u64* __restrict__ stats)
{
    __shared__ float qs[ROWS*ND];                 // 4KB
    __shared__ unsigned int hist[GSZ][4096];      // 64KB
    __shared__ int scol[GSZ][TK];
    __shared__ float sval[GSZ][TK], sx[GSZ][TK], sy[GSZ][TK], sz[GSZ][TK], sdist[GSZ][TK];
    __shared__ u64 vadd[GSZ][81];
    __shared__ unsigned int vcnt[GSZ][81];
    __shared__ float voxn[GSZ][81];
    __shared__ int eqcol[GSZ][256];
    __shared__ unsigned int pfx[GSZ];
    __shared__ int kg[GSZ], cnt_sel[GSZ], cnt_eq[GSZ];
    __shared__ u64 wg_ocsum[8], wg_ocsq[8], wg_km1[4], wg_km2[16];

    const int t = threadIdx.x;
    const int blk = blockIdx.x;
    // XCD-aware: batch 0 -> XCDs 0-3, batch 1 -> XCDs 4-7 (fmap2 4MB fits one L2)
    const int xcd = blk & 7;
    const int b = xcd >> 2;
    const int i0 = ((((xcd & 3) << 8) | (blk >> 3))) * ROWS;

    {   // load fmap1 rows (once)
        const int d = t >> 3, r = t & 7;
        qs[r*ND + d] = fmap1[((size_t)b*ND + d)*NN + (i0 + r)];
    }
    if (t < 8){ wg_ocsum[t]=0ull; wg_ocsq[t]=0ull; }
    if (t < 4) wg_km1[t]=0ull;
    if (t < 16) wg_km2[t]=0ull;
    __syncthreads();

    // ---- GEMM: 8 rows x 8192 cols; thread t owns cols [4t,4t+4) and [4096+4t,+4) ----
    float acc[ROWS][8];
    #pragma unroll
    for (int r=0;r<ROWS;r++)
        #pragma unroll
        for (int j=0;j<8;j++) acc[r][j]=0.f;

    const float* f2b = fmap2 + (size_t)b*ND*NN;
    const float* pA = f2b + 4*t;
    float4 a0 = *(const float4*)(pA);
    float4 a1 = *(const float4*)(pA + 4096);
    float4 b0 = *(const float4*)(pA + NN);
    float4 b1v = *(const float4*)(pA + NN + 4096);
    pA += 2*NN;
    for (int d=0; d<ND-2; d+=2){
        float4 na0 = *(const float4*)(pA);
        float4 na1 = *(const float4*)(pA + 4096);
        float4 nb0 = *(const float4*)(pA + NN);
        float4 nb1 = *(const float4*)(pA + NN + 4096);
        pA += 2*NN;
        #pragma unroll
        for (int r=0;r<ROWS;r++){
            const float2 q = *(const float2*)&qs[r*ND + d];
            acc[r][0] = fmaf(q.x, a0.x, fmaf(q.y, b0.x, acc[r][0]));
            acc[r][1] = fmaf(q.x, a0.y, fmaf(q.y, b0.y, acc[r][1]));
            acc[r][2] = fmaf(q.x, a0.z, fmaf(q.y, b0.z, acc[r][2]));
            acc[r][3] = fmaf(q.x, a0.w, fmaf(q.y, b0.w, acc[r][3]));
            acc[r][4] = fmaf(q.x, a1.x, fmaf(q.y, b1v.x, acc[r][4]));
            acc[r][5] = fmaf(q.x, a1.y, fmaf(q.y, b1v.y, acc[r][5]));
            acc[r][6] = fmaf(q.x, a1.z, fmaf(q.y, b1v.z, acc[r][6]));
            acc[r][7] = fmaf(q.x, a1.w, fmaf(q.y, b1v.w, acc[r][7]));
        }
        a0=na0; a1=na1; b0=nb0; b1v=nb1;
    }
    {   // last dim pair
        const int d = ND-2;
        #pragma unroll
        for (int r=0;r<ROWS;r++){
            const float2 q = *(const float2*)&qs[r*ND + d];
            acc[r][0] = fmaf(q.x, a0.x, fmaf(q.y, b0.x, acc[r][0]));
            acc[r][1] = fmaf(q.x, a0.y, fmaf(q.y, b0.y, acc[r][1]));
            acc[r][2] = fmaf(q.x, a0.z, fmaf(q.y, b0.z, acc[r][2]));
            acc[r][3] = fmaf(q.x, a0.w, fmaf(q.y, b0.w, acc[r][3]));
            acc[r][4] = fmaf(q.x, a1.x, fmaf(q.y, b1v.x, acc[r][4]));
            acc[r][5] = fmaf(q.x, a1.y, fmaf(q.y, b1v.y, acc[r][5]));
            acc[r][6] = fmaf(q.x, a1.z, fmaf(q.y, b1v.z, acc[r][6]));
            acc[r][7] = fmaf(q.x, a1.w, fmaf(q.y, b1v.w, acc[r][7]));
        }
    }
    const float scl = 0.088388347648318447f; // 1/sqrt(128)
    #pragma unroll
    for (int r=0;r<ROWS;r++)
        #pragma unroll
        for (int j=0;j<8;j++) acc[r][j]*=scl;

    // scan helper: wave g (t<256) scans hist[g], updates kg/pfx
    auto scan_pass = [&](int nb, int bits){
        if (t < 64*GSZ){
            const int g = t >> 6, lane = t & 63;
            const int per = nb >> 6;
            const int base = lane * per;
            unsigned tot = 0;
            for (int i=0;i<per;i+=4){
                const uint4 h4 = *(const uint4*)&hist[g][base+i];
                tot += h4.x+h4.y+h4.z+h4.w;
            }
            unsigned S = tot;
            #pragma unroll
            for (int off=1; off<64; off<<=1){
                const unsigned o = __shfl_down(S, off);
                if (lane+off < 64) S += o;
            }
            const int k = kg[g];
            if ((int)S >= k && (int)(S-tot) < k){
                int run = (int)(S - tot);
                int B = 0, hB = 0;
                for (int i=per-1;i>=0;--i){
                    const int h = (int)hist[g][base+i];
                    run += h;
                    if (run >= k){ B = base+i; hB = h; break; }
                }
                kg[g] = k - (run - hB);
                pfx[g] = (pfx[g] << bits) | (unsigned)B;
            }
        }
    };

    uint4* hz = (uint4*)&hist[0][0];
    const uint4 z4 = {0u,0u,0u,0u};

    for (int grp=0; grp<2; ++grp){
        // ======== pass 0 (bits 31:20) ========
        for (int z=t; z<GSZ*1024; z+=NT) hz[z] = z4;
        if (t < GSZ){ kg[t]=TK; pfx[t]=0u; cnt_sel[t]=0; cnt_eq[t]=0; }
        __syncthreads();
        #pragma unroll
        for (int g=0; g<GSZ; ++g)
            #pragma unroll
            for (int j=0;j<8;j++)
                atomicAdd(&hist[g][f2key(acc[grp*GSZ+g][j])>>20], 1u);
        __syncthreads();
        scan_pass(4096, 12);
        __syncthreads();
        // ======== pass 1 (bits 19:8) ========
        for (int z=t; z<GSZ*1024; z+=NT) hz[z] = z4;
        __syncthreads();
        #pragma unroll
        for (int g=0; g<GSZ; ++g){
            const unsigned pf = pfx[g];
            #pragma unroll
            for (int j=0;j<8;j++){
                const unsigned key = f2key(acc[grp*GSZ+g][j]);
                if ((key>>20) == pf) atomicAdd(&hist[g][(key>>8)&4095], 1u);
            }
        }
        __syncthreads();
        scan_pass(4096, 12);
        __syncthreads();
        // ======== pass 2 (bits 7:0) ========
        if (t < 256){ *(uint4*)&hist[t>>6][(t&63)*4] = z4; }
        __syncthreads();
        #pragma unroll
        for (int g=0; g<GSZ; ++g){
            const unsigned pf = pfx[g];
            #pragma unroll
            for (int j=0;j<8;j++){
                const unsigned key = f2key(acc[grp*GSZ+g][j]);
                if ((key>>8) == pf) atomicAdd(&hist[g][key&255], 1u);
            }
        }
        __syncthreads();
        scan_pass(256, 8);
        __syncthreads();
        // ======== collect: strict winners + eq candidates ========
        #pragma unroll
        for (int g=0; g<GSZ; ++g){
            const unsigned T = pfx[g];
            #pragma unroll
            for (int j=0;j<8;j++){
                const unsigned key = f2key(acc[grp*GSZ+g][j]);
                if (key > T){
                    const int p = atomicAdd(&cnt_sel[g], 1);
                    scol[g][p] = ((j>>2)<<12) | ((t<<2) + (j&3));
                    sval[g][p] = acc[grp*GSZ+g][j];
                } else if (key == T){
                    const int p = atomicAdd(&cnt_eq[g], 1);
                    if (p < 256) eqcol[g][p] = ((j>>2)<<12) | ((t<<2) + (j&3));
                }
            }
        }
        __syncthreads();
        const int gq = t >> 8, i2 = t & 255;
        const int k4 = TK - cnt_sel[gq];          // uniform read BEFORE eq atomics
        int m = cnt_eq[gq]; if (m > 256) m = 256;
        if (i2 < 81){ vadd[gq][i2]=0ull; vcnt[gq][i2]=0u; }
        __syncthreads();
        {   // eq resolution (first k4 by column order)
            const unsigned T = pfx[gq];
            if (i2 < m){
                const int myc = eqcol[gq][i2];
                int rank = 0;
                for (int u2=0; u2<m; ++u2) rank += (eqcol[gq][u2] < myc) ? 1 : 0;
                if (rank < k4){
                    const int p = atomicAdd(&cnt_sel[gq], 1);
                    scol[gq][p] = myc;
                    sval[gq][p] = __uint_as_float((T & 0x80000000u) ? (T ^ 0x80000000u) : ~T);
                }
            }
        }
        __syncthreads();
        // ======== xyz gather + dist + voxel atomics ========
        if (i2 < TK){
            const int i = i0 + grp*GSZ + gq;
            const float cx = coords[((size_t)b*NN + i)*3 + 0];
            const float cy = coords[((size_t)b*NN + i)*3 + 1];
            const float cz = coords[((size_t)b*NN + i)*3 + 2];
            const float* pp = &xyz2[((size_t)b*NN + scol[gq][i2])*3];
            const float px = pp[0], py = pp[1], pz = pp[2];
            sx[gq][i2]=px; sy[gq][i2]=py; sz[gq][i2]=pz;
            const float dx = px-cx, dy = py-cy, dz = pz-cz;
            sdist[gq][i2] = dx*dx + dy*dy + dz*dz;
            const float val = sval[gq][i2];
            #pragma unroll
            for (int lvl=0; lvl<3; ++lvl){
                const float rs = 0.25f * (float)(1<<lvl);
                const float fx = rintf(dx/rs), fy = rintf(dy/rs), fz = rintf(dz/rs);
                if (fabsf(fx)<=1.f && fabsf(fy)<=1.f && fabsf(fz)<=1.f){
                    const int bin = lvl*27 + ((int)fx+1)*9 + ((int)fy+1)*3 + ((int)fz+1);
                    atomicAdd(&vadd[gq][bin], (u64)llrintf(val*67108864.f));
                    atomicAdd(&vcnt[gq][bin], 1u);
                }
            }
        }
        __syncthreads();
        if (i2 < 81){
            const float addv = (float)(i64)vadd[gq][i2] * (1.f/67108864.f);
            float c = (float)vcnt[gq][i2]; if (c < 1.f) c = 1.f;
            voxn[gq][i2] = addv / c;
        }
        __syncthreads();
        // ======== h (threads 0..511) || knn (threads 512..1023) ========
        if (t < 512){
            const int g = t >> 7, c = t & 127;
            const int i = i0 + grp*GSZ + g;
            float h = b1[c];
            #pragma unroll
            for (int j=0;j<81;j++) h = fmaf(w1[c*81+j], voxn[g][j], h);
            ws_h[((size_t)b*NN + i)*ND + c] = h;
            long long s1 = llrintf(h*1048576.f);
            long long s2 = llrintf(h*h*1048576.f);
            #pragma unroll
            for (int off=1; off<16; off<<=1){
                s1 += __shfl_xor(s1, off);
                s2 += __shfl_xor(s2, off);
            }
            if ((t & 15) == 0){
                atomicAdd(&wg_ocsum[c>>4], (u64)s1);
                atomicAdd(&wg_ocsq[c>>4],  (u64)s2);
            }
        } else {
            const int t2 = t - 512;
            const int g = t2 >> 7, i2k = t2 & 127;
            const int i = i0 + grp*GSZ + g;
            const float cx = coords[((size_t)b*NN + i)*3 + 0];
            const float cy = coords[((size_t)b*NN + i)*3 + 1];
            const float cz = coords[((size_t)b*NN + i)*3 + 2];
            float kv0=0.f, kv1=0.f, kv2=0.f, kv3=0.f;
            const float my = sdist[g][i2k];
            int rank = 0;
            for (int u2=0; u2<TK; ++u2){
                const float o = sdist[g][u2];
                rank += (o < my || (o == my && u2 < i2k)) ? 1 : 0;
            }
            if (rank < KNNK){
                kv0 = sval[g][i2k];
                kv1 = sx[g][i2k]-cx; kv2 = sy[g][i2k]-cy; kv3 = sz[g][i2k]-cz;
                float* kp = &ws_kin[(((size_t)b*NN + i)*KNNK + rank)*4];
                kp[0]=kv0; kp[1]=kv1; kp[2]=kv2; kp[3]=kv3;
            }
            const float kvs[4] = {kv0,kv1,kv2,kv3};
            #pragma unroll
            for (int q=0;q<20;q++){
                const int a2 = (q<4) ? q : ((q-4)>>2);
                const int b2i = (q<4) ? 0 : ((q-4)&3);
                const float prod = (q<4) ? kvs[a2] : kvs[a2]*kvs[b2i];
                long long v = llrintf(prod*1048576.f);
                #pragma unroll
                for (int off=1; off<64; off<<=1) v += __shfl_xor(v, off);
                if ((t & 63) == 0){
                    if (q<4) atomicAdd(&wg_km1[q], (u64)v);
                    else     atomicAdd(&wg_km2[q-4], (u64)v);
                }
            }
        }
        __syncthreads();
    }

    if (t < 8){ atomicAdd(&stats[b*8 + t], wg_ocsum[t]); atomicAdd(&stats[16 + b*8 + t], wg_ocsq[t]); }
    if (t < 4){ atomicAdd(&stats[32 + b*4 + t], wg_km1[t]); }
    if (t < 16){ atomicAdd(&stats[40 + b*16 + t], wg_km2[t]); }
}

// ---------------- K2: finalize GN statistics (f64, tiny) ----------------
__global__ void k2_stats(const u64* __restrict__ stats, float* __restrict__ fstats,
                         const float* __restrict__ kcw, const float* __restrict__ kcb)
{
    const int t = threadIdx.x;
    if (t < 16){
        const double S = (double)(i64)stats[t];
        const double Q = (double)(i64)stats[16+t];
        const double cnt = 16.0*8192.0;
        const double mean = S / 1048576.0 / cnt;
        const double var  = Q / 1048576.0 / cnt - mean*mean;
        fstats[t]    = (float)mean;
        fstats[16+t] = (float)(1.0/sqrt(var + 1e-5));
    }
    if (t >= 32 && t < 48){
        const int u = t - 32;
        const int b = u >> 3, g = u & 7;
        double M1[4], M2[4][4];
        for (int a=0;a<4;a++) M1[a] = (double)(i64)stats[32 + b*4 + a] / 1048576.0;
        for (int a=0;a<4;a++) for (int c=0;c<4;c++)
            M2[a][c] = (double)(i64)stats[40 + b*16 + a*4 + c] / 1048576.0;
        const double cnt = 8192.0*32.0;
        double SUM=0.0, SSQ=0.0;
        for (int c = g*8; c < g*8+8; ++c){
            double wv[4]; for (int a=0;a<4;a++) wv[a] = (double)kcw[c*4+a];
            const double bc = (double)kcb[c];
            double sc = bc*cnt;
            double qc = bc*bc*cnt;
            for (int a=0;a<4;a++){
                sc += wv[a]*M1[a];
                qc += 2.0*bc*wv[a]*M1[a];
                for (int e=0;e<4;e++) qc += wv[a]*wv[e]*M2[a][e];
            }
            SUM += sc; SSQ += qc;
        }
        const double denom = 8.0*cnt;
        const double mean = SUM/denom;
        const double var  = SSQ/denom - mean*mean;
        fstats[32+u] = (float)mean;
        fstats[48+u] = (float)(1.0/sqrt(var + 1e-5));
    }
}

// ---------------- K3a: GN + PReLU + W2 (vox branch) ----------------
__global__ __launch_bounds__(256) void k3a_vox(
    const float* __restrict__ ws_h, const float* __restrict__ fstats,
    const float* __restrict__ gnw, const float* __restrict__ gnb,
    const float* __restrict__ pr, const float* __restrict__ w2,
    const float* __restrict__ b2, float* __restrict__ out)
{
    __shared__ float p[16][ND];
    __shared__ float w2s[64][ND+1];
    const int t = threadIdx.x;
    const int base = blockIdx.x * 16;
    const int b = base >> 13;
    for (int u=t; u<64*ND; u+=256) w2s[u>>7][u&127] = w2[u];
    const float a = pr[0];
    for (int u=t; u<16*ND; u+=256){
        const int pt=u>>7, c=u&127, g=c>>4;
        const float hv = ws_h[(size_t)(base+pt)*ND + c];
        const float hn = (hv - fstats[b*8+g])*fstats[16+b*8+g]*gnw[c] + gnb[c];
        p[pt][c] = hn>=0.f ? hn : a*hn;
    }
    __syncthreads();
    const int o = t & 63, wv = t >> 6;
    float acc0=b2[o], acc1=acc0, acc2=acc0, acc3=acc0;
    for (int c=0;c<ND;c++){
        const float w = w2s[o][c];
        acc0 = fmaf(w, p[wv*4+0][c], acc0);
        acc1 = fmaf(w, p[wv*4+1][c], acc1);
        acc2 = fmaf(w, p[wv*4+2][c], acc2);
        acc3 = fmaf(w, p[wv*4+3][c], acc3);
    }
    const float4 res = {acc0,acc1,acc2,acc3};
    *(float4*)&out[((size_t)b*64 + o)*NN + (base & (NN-1)) + wv*4] = res;
}

// ---------------- K3b: knn conv + GN + PReLU + maxpool + ko ----------------
__global__ __launch_bounds__(256) void k3b_knn(
    const float* __restrict__ ws_kin, const float* __restrict__ fstats,
    const float* __restrict__ kcw, const float* __restrict__ kcb,
    const float* __restrict__ gnw, const float* __restrict__ gnb,
    const float* __restrict__ pr, const float* __restrict__ kow,
    const float* __restrict__ kob, float* __restrict__ out)
{
    __shared__ float skin[16][KNNK*4+4];
    __shared__ float kml[16][65];
    __shared__ float kos[64][65];
    const int t = threadIdx.x;
    const int base = blockIdx.x * 16;
    const int b = base >> 13;
    const float4* kin4 = (const float4*)ws_kin;
    for (int v=t; v<16*KNNK; v+=256){
        const int pt = v>>5, q = v&31;
        const float4 val = kin4[(size_t)(base+pt)*KNNK + q];
        *(float4*)&skin[pt][q*4] = val;
    }
    for (int u=t; u<4096; u+=256) kos[u>>6][u&63] = kow[u];
    __syncthreads();
    const float a = pr[0];
    {
        const int pt = t>>4, cb = (t&15)*4;
        #pragma unroll
        for (int cc=0; cc<4; ++cc){
            const int c = cb+cc, g = c>>3;
            const float mean = fstats[32+b*8+g], rstd = fstats[48+b*8+g];
            const float gw = rstd*gnw[c], gb = gnb[c]-mean*gw;
            const float w0=kcw[c*4], w1v=kcw[c*4+1], w2v=kcw[c*4+2], w3=kcw[c*4+3], bc=kcb[c];
            float mx = -3.0e38f;
            for (int kk=0;kk<KNNK;kk++){
                const float4 sv = *(const float4*)&skin[pt][kk*4];
                float kf = fmaf(w0,sv.x, fmaf(w1v,sv.y, fmaf(w2v,sv.z, fmaf(w3,sv.w, bc))));
                float hn = kf*gw + gb;
                hn = hn>=0.f ? hn : a*hn;
                mx = fmaxf(mx, hn);
            }
            kml[pt][c] = mx;
        }
    }
    __syncthreads();
    const int o = t & 63, wv = t >> 6;
    float acc0=kob[o], acc1=acc0, acc2=acc0, acc3=acc0;
    for (int c=0;c<64;c++){
        const float w = kos[o][c];
        acc0 = fmaf(w, kml[wv*4+0][c], acc0);
        acc1 = fmaf(w, kml[wv*4+1][c], acc1);
        acc2 = fmaf(w, kml[wv*4+2][c], acc2);
        acc3 = fmaf(w, kml[wv*4+3][c], acc3);
    }
    float* op = &out[((size_t)b*64 + o)*NN + (base & (NN-1)) + wv*4];
    float4 cur = *(float4*)op;
    cur.x += acc0; cur.y += acc1; cur.z += acc2; cur.w += acc3;
    *(float4*)op = cur;
}

extern "C" void kernel_launch(void* const* d_in, const int* in_sizes, int n_in,
                              void* d_out, int out_size, void* d_ws, size_t ws_size,
                              hipStream_t stream)
{
    const float* fmap1   = (const float*)d_in[0];
    const float* fmap2   = (const float*)d_in[1];
    const float* xyz2    = (const float*)d_in[2];
    const float* coords  = (const float*)d_in[3];
    const float* oc_w1   = (const float*)d_in[4];
    const float* oc_b1   = (const float*)d_in[5];
    const float* oc_gn_w = (const float*)d_in[6];
    const float* oc_gn_b = (const float*)d_in[7];
    const float* oc_pr   = (const float*)d_in[8];
    const float* oc_w2   = (const float*)d_in[9];
    const float* oc_b2   = (const float*)d_in[10];
    const float* kc_w    = (const float*)d_in[11];
    const float* kc_b    = (const float*)d_in[12];
    const float* kc_gn_w = (const float*)d_in[13];
    const float* kc_gn_b = (const float*)d_in[14];
    const float* kc_pr   = (const float*)d_in[15];
    const float* ko_w    = (const float*)d_in[16];
    const float* ko_b    = (const float*)d_in[17];

    char* ws = (char*)d_ws;
    float* ws_h   = (float*)ws;
    float* ws_kin = (float*)(ws + (size_t)8*1024*1024);
    u64*   stats  = (u64*)  (ws + (size_t)16*1024*1024);
    float* fstats = (float*)(ws + (size_t)16*1024*1024 + 1024);
    float* out    = (float*)d_out;

    k0_zero<<<dim3(1), dim3(128), 0, stream>>>(stats);
    k1_corr_topk<<<dim3(2048), dim3(NT), 0, stream>>>(
        fmap1, fmap2, xyz2, coords, oc_w1, oc_b1, ws_h, ws_kin, stats);
    k2_stats<<<dim3(1), dim3(64), 0, stream>>>(stats, fstats, kc_w, kc_b);
    k3a_vox<<<dim3(1024), dim3(256), 0, stream>>>(
        ws_h, fstats, oc_gn_w, oc_gn_b, oc_pr, oc_w2, oc_b2, out);
    k3b_knn<<<dim3(1024), dim3(256), 0, stream>>>(
        ws_kin, fstats, kc_w, kc_b, kc_gn_w, kc_gn_b, kc_pr, ko_w, ko_b, out);
}